// Round 1
// baseline (1953.858 us; speedup 1.0000x reference)
//
#include <hip/hip_runtime.h>
#include <math.h>

#define B_   16
#define S_   4096
#define I_   128
#define HD_  384
#define M_   256
#define K_   384   // M_+I_
#define EPS_ 1e-5f

// ---------------------------------------------------------------- K1: u_pre + BN(u)
__global__ __launch_bounds__(256) void k_upre(const float* __restrict__ x,
                                              const float* __restrict__ wu,
                                              const float* __restrict__ wub,
                                              const float* __restrict__ g_u,
                                              const float* __restrict__ b_u,
                                              const float* __restrict__ mu_u,
                                              const float* __restrict__ var_u,
                                              float* __restrict__ u_bn) {
    __shared__ float w[I_];
    int tid = threadIdx.x;
    if (tid < I_) w[tid] = wu[tid];
    __syncthreads();
    int row = blockIdx.x * 256 + tid;            // 0..65535
    const float4* xr = (const float4*)(x + (size_t)row * I_);
    const float4* w4 = (const float4*)w;
    float4 s4 = {0.f, 0.f, 0.f, 0.f};
    #pragma unroll
    for (int i = 0; i < I_ / 4; i++) {
        float4 xv = xr[i], wv = w4[i];
        s4.x += xv.x * wv.x; s4.y += xv.y * wv.y;
        s4.z += xv.z * wv.z; s4.w += xv.w * wv.w;
    }
    float s = (s4.x + s4.y) + (s4.z + s4.w) + wub[0];
    float rs = 1.0f / sqrtf(var_u[0] + EPS_);
    u_bn[row] = g_u[0] * (s - mu_u[0]) * rs + b_u[0];
}

// ---------------------------------------------------------------- K2: u-LIF (chunked, warm-up 128)
__global__ __launch_bounds__(256) void k_ulif(const float* __restrict__ u_bn,
                                              float* __restrict__ u_spk) {
    int b = blockIdx.x, tid = threadIdx.x;
    int t0 = tid * 16;
    int start = t0 - 128; if (start < 0) start = 0;
    const float* ub = u_bn + (size_t)b * S_;
    float v = 0.f;
    for (int t = start; t < t0 + 16; t++) {
        float xv = ub[t];
        v = v + (xv - v) * 0.5f;
        float sp = (v - 1.0f) >= 0.0f ? 1.0f : 0.0f;
        if (t >= t0) u_spk[(size_t)b * S_ + t] = sp;
        v = v * (1.0f - sp);
    }
}

// ---------------------------------------------------------------- K2b: compact sorted spike lists
__global__ __launch_bounds__(256) void k_compact(const float* __restrict__ u_spk,
                                                 int* __restrict__ spk_idx,
                                                 int* __restrict__ spk_cnt) {
    __shared__ int wcnt[4];
    __shared__ int base;
    int b = blockIdx.x, tid = threadIdx.x;
    int lane = tid & 63, w = tid >> 6;
    if (tid == 0) base = 0;
    __syncthreads();
    for (int r = 0; r < 16; r++) {
        int t = r * 256 + tid;
        bool f = u_spk[(size_t)b * S_ + t] > 0.5f;
        unsigned long long bal = __ballot(f);
        int pre = __popcll(bal & (((unsigned long long)1 << lane) - 1ull));
        if (lane == 0) wcnt[w] = __popcll(bal);
        __syncthreads();
        int off = base;
        for (int i = 0; i < w; i++) off += wcnt[i];
        if (f) spk_idx[(size_t)b * S_ + off + pre] = t;
        __syncthreads();
        if (tid == 0) base += wcnt[0] + wcnt[1] + wcnt[2] + wcnt[3];
        __syncthreads();
    }
    if (tid == 0) spk_cnt[b] = base;
}

// ---------------------------------------------------------------- K3: sparse conv + BN(m)  -> m_bn [B,M,S]
__global__ __launch_bounds__(256) void k_conv(const float* __restrict__ H,
                                              const int* __restrict__ spk_idx,
                                              const int* __restrict__ spk_cnt,
                                              const float* __restrict__ g_m,
                                              const float* __restrict__ b_m,
                                              const float* __restrict__ mu_m,
                                              const float* __restrict__ var_m,
                                              float* __restrict__ m_bn) {
    __shared__ float Hrow[S_];
    __shared__ int spk[S_];
    int bid = blockIdx.x;
    int b = bid >> 8, ch = bid & 255;
    int tid = threadIdx.x;
    const float4* Hv = (const float4*)(H + (size_t)ch * S_);
    float4* Hl = (float4*)Hrow;
    for (int i = tid; i < S_ / 4; i += 256) Hl[i] = Hv[i];
    int n = spk_cnt[b];
    const int* sl = spk_idx + (size_t)b * S_;
    for (int i = tid; i < n; i += 256) spk[i] = sl[i];
    __syncthreads();
    float g = g_m[ch], bb = b_m[ch], mu = mu_m[ch];
    float rs = 1.0f / sqrtf(var_m[ch] + EPS_);
    float* out = m_bn + ((size_t)b * M_ + ch) * S_;
    for (int t = tid; t < S_; t += 256) {
        float s = 0.f;
        for (int j = 0; j < n; j++) {
            int tau = spk[j];
            if (tau > t) break;
            s += Hrow[t - tau];
        }
        out[t] = g * (s - mu) * rs + bb;
    }
}

// ---------------------------------------------------------------- K5: m-LIF (chunk 512, warm-up 128) -> m_s [B,S,M]
__global__ __launch_bounds__(256) void k_mlif(const float* __restrict__ m_bn,
                                              float* __restrict__ m_s) {
    int b = blockIdx.x;
    int ch = blockIdx.y * 64 + threadIdx.x;
    int c = blockIdx.z * 4 + threadIdx.y;
    int t0 = c * 512;
    int start = t0 - 128; if (start < 0) start = 0;
    const float* src = m_bn + ((size_t)b * M_ + ch) * S_;
    float v = 0.f;
    for (int t = start; t < t0 + 512; t += 4) {
        float4 xv = *(const float4*)(src + t);
        float xs[4] = {xv.x, xv.y, xv.z, xv.w};
        #pragma unroll
        for (int u = 0; u < 4; u++) {
            int t2 = t + u;
            v = v + (xs[u] - v) * 0.5f;
            float sp = (v - 1.0f) >= 0.0f ? 1.0f : 0.0f;
            if (t2 >= t0) m_s[((size_t)b * S_ + t2) * M_ + ch] = sp;
            v = v * (1.0f - sp);
        }
    }
}

// ---------------------------------------------------------------- K6: h GEMM (fp32) + bias + BN(h) -> h_bn [B*S, HD]
__global__ __launch_bounds__(256) void k_hgemm(const float* __restrict__ m_s,
                                               const float* __restrict__ x,
                                               const float* __restrict__ W,
                                               const float* __restrict__ Wb,
                                               const float* __restrict__ g_h,
                                               const float* __restrict__ b_h,
                                               const float* __restrict__ mu_h,
                                               const float* __restrict__ var_h,
                                               float* __restrict__ h_bn) {
    __shared__ float AsT[64 * 68];
    __shared__ float Bs[64 * 68];
    int tid = threadIdx.x;
    int row0 = blockIdx.x * 64, col0 = blockIdx.y * 64;
    int tx = tid & 15, ty = tid >> 4;
    int lr = tid >> 2, kq = tid & 3;
    float acc[4][4] = {};
    for (int kt = 0; kt < 6; kt++) {
        const float* Abase;
        if (kt < 4) Abase = m_s + (size_t)(row0 + lr) * M_ + kt * 64;
        else        Abase = x   + (size_t)(row0 + lr) * I_ + (kt - 4) * 64;
        #pragma unroll
        for (int i = 0; i < 4; i++) {
            int kl = kq * 16 + i * 4;
            float4 v = *(const float4*)(Abase + kl);
            AsT[(kl + 0) * 68 + lr] = v.x;
            AsT[(kl + 1) * 68 + lr] = v.y;
            AsT[(kl + 2) * 68 + lr] = v.z;
            AsT[(kl + 3) * 68 + lr] = v.w;
        }
        const float* Bbase = W + (size_t)(col0 + lr) * K_ + kt * 64;
        #pragma unroll
        for (int i = 0; i < 4; i++) {
            int kl = kq * 16 + i * 4;
            float4 v = *(const float4*)(Bbase + kl);
            Bs[(kl + 0) * 68 + lr] = v.x;
            Bs[(kl + 1) * 68 + lr] = v.y;
            Bs[(kl + 2) * 68 + lr] = v.z;
            Bs[(kl + 3) * 68 + lr] = v.w;
        }
        __syncthreads();
        #pragma unroll 4
        for (int kk = 0; kk < 64; kk++) {
            float4 a  = *(const float4*)&AsT[kk * 68 + ty * 4];
            float4 bv = *(const float4*)&Bs[kk * 68 + tx * 4];
            float av[4] = {a.x, a.y, a.z, a.w};
            float bw[4] = {bv.x, bv.y, bv.z, bv.w};
            #pragma unroll
            for (int r = 0; r < 4; r++)
                #pragma unroll
                for (int cjj = 0; cjj < 4; cjj++)
                    acc[r][cjj] += av[r] * bw[cjj];
        }
        __syncthreads();
    }
    int col = col0 + tx * 4;
    float4 g4  = *(const float4*)(g_h + col);
    float4 b4  = *(const float4*)(b_h + col);
    float4 mu4 = *(const float4*)(mu_h + col);
    float4 va4 = *(const float4*)(var_h + col);
    float4 wb4 = *(const float4*)(Wb + col);
    float gg[4]  = {g4.x, g4.y, g4.z, g4.w};
    float bbv[4] = {b4.x, b4.y, b4.z, b4.w};
    float mm[4]  = {mu4.x, mu4.y, mu4.z, mu4.w};
    float vv[4]  = {va4.x, va4.y, va4.z, va4.w};
    float wb[4]  = {wb4.x, wb4.y, wb4.z, wb4.w};
    float rs[4];
    #pragma unroll
    for (int j = 0; j < 4; j++) rs[j] = 1.0f / sqrtf(vv[j] + EPS_);
    #pragma unroll
    for (int r = 0; r < 4; r++) {
        int row = row0 + ty * 4 + r;
        float o[4];
        #pragma unroll
        for (int j = 0; j < 4; j++)
            o[j] = gg[j] * ((acc[r][j] + wb[j]) - mm[j]) * rs[j] + bbv[j];
        float4 o4 = {o[0], o[1], o[2], o[3]};
        *(float4*)(h_bn + (size_t)row * HD_ + col) = o4;
    }
}

// ---------------------------------------------------------------- K7: h-LIF (chunk 512, warm-up 128) -> out
__global__ __launch_bounds__(256) void k_hlif(const float* __restrict__ h_bn,
                                              float* __restrict__ out) {
    int b = blockIdx.x;
    int j = blockIdx.y * 64 + threadIdx.x;
    int c = blockIdx.z * 4 + threadIdx.y;
    int t0 = c * 512;
    int start = t0 - 128; if (start < 0) start = 0;
    float* hn = out + (size_t)B_ * S_ * HD_;
    float v = 0.f;
    for (int t = start; t < t0 + 512; t++) {
        float xv = h_bn[((size_t)b * S_ + t) * HD_ + j];
        v = v + (xv - v) * 0.5f;
        float sp = (v - 1.0f) >= 0.0f ? 1.0f : 0.0f;
        if (t >= t0) {
            out[((size_t)b * S_ + t) * HD_ + j] = sp;
            if (t == S_ - 1) hn[(size_t)b * HD_ + j] = sp;
        }
        v = v * (1.0f - sp);
    }
}

// ---------------------------------------------------------------- launch
extern "C" void kernel_launch(void* const* d_in, const int* in_sizes, int n_in,
                              void* d_out, int out_size, void* d_ws, size_t ws_size,
                              hipStream_t stream) {
    const float* x     = (const float*)d_in[0];
    const float* H     = (const float*)d_in[1];
    const float* Wu    = (const float*)d_in[2];
    const float* Wub   = (const float*)d_in[3];
    const float* Wh    = (const float*)d_in[4];
    const float* Whb   = (const float*)d_in[5];
    const float* g_u   = (const float*)d_in[6];
    const float* b_u   = (const float*)d_in[7];
    const float* mu_u  = (const float*)d_in[8];
    const float* var_u = (const float*)d_in[9];
    const float* g_m   = (const float*)d_in[10];
    const float* b_m   = (const float*)d_in[11];
    const float* mu_m  = (const float*)d_in[12];
    const float* var_m = (const float*)d_in[13];
    const float* g_h   = (const float*)d_in[14];
    const float* b_h   = (const float*)d_in[15];
    const float* mu_h  = (const float*)d_in[16];
    const float* var_h = (const float*)d_in[17];

    float* ws    = (float*)d_ws;
    float* u_bn  = ws;                               // 65536
    float* u_spk = ws + 65536;                       // 65536
    int*   spk_idx = (int*)(ws + 131072);            // 65536 ints
    int*   spk_cnt = (int*)(ws + 196608);            // 16 ints
    float* m_bn  = ws + 200704;                      // 16777216  [B,M,S]
    float* m_s   = m_bn + 16777216;                  // 16777216  [B,S,M]
    float* h_bn  = m_s + 16777216;                   // 25165824  [B*S,HD]

    k_upre<<<dim3(256), dim3(256), 0, stream>>>(x, Wu, Wub, g_u, b_u, mu_u, var_u, u_bn);
    k_ulif<<<dim3(16), dim3(256), 0, stream>>>(u_bn, u_spk);
    k_compact<<<dim3(16), dim3(256), 0, stream>>>(u_spk, spk_idx, spk_cnt);
    k_conv<<<dim3(4096), dim3(256), 0, stream>>>(H, spk_idx, spk_cnt,
                                                 g_m, b_m, mu_m, var_m, m_bn);
    k_mlif<<<dim3(16, 4, 2), dim3(64, 4), 0, stream>>>(m_bn, m_s);
    k_hgemm<<<dim3(1024, 6), dim3(256), 0, stream>>>(m_s, x, Wh, Whb,
                                                     g_h, b_h, mu_h, var_h, h_bn);
    k_hlif<<<dim3(16, 6, 2), dim3(64, 4), 0, stream>>>(h_bn, (float*)d_out);
}

// Round 2
// 867.913 us; speedup vs baseline: 2.2512x; 2.2512x over previous
//
#include <hip/hip_runtime.h>
#include <math.h>

#define B_   16
#define S_   4096
#define I_   128
#define HD_  384
#define M_   256
#define K_   384   // M_+I_
#define EPS_ 1e-5f

// ---------------------------------------------------------------- K1: u_pre + BN(u)
__global__ __launch_bounds__(256) void k_upre(const float* __restrict__ x,
                                              const float* __restrict__ wu,
                                              const float* __restrict__ wub,
                                              const float* __restrict__ g_u,
                                              const float* __restrict__ b_u,
                                              const float* __restrict__ mu_u,
                                              const float* __restrict__ var_u,
                                              float* __restrict__ u_bn) {
    __shared__ float w[I_];
    int tid = threadIdx.x;
    if (tid < I_) w[tid] = wu[tid];
    __syncthreads();
    int row = blockIdx.x * 256 + tid;            // 0..65535
    const float4* xr = (const float4*)(x + (size_t)row * I_);
    const float4* w4 = (const float4*)w;
    float4 s4 = {0.f, 0.f, 0.f, 0.f};
    #pragma unroll
    for (int i = 0; i < I_ / 4; i++) {
        float4 xv = xr[i], wv = w4[i];
        s4.x += xv.x * wv.x; s4.y += xv.y * wv.y;
        s4.z += xv.z * wv.z; s4.w += xv.w * wv.w;
    }
    float s = (s4.x + s4.y) + (s4.z + s4.w) + wub[0];
    float rs = 1.0f / sqrtf(var_u[0] + EPS_);
    u_bn[row] = g_u[0] * (s - mu_u[0]) * rs + b_u[0];
}

// ---------------------------------------------------------------- K2: u-LIF (chunk 4, warm-up 128)
__global__ __launch_bounds__(256) void k_ulif(const float* __restrict__ u_bn,
                                              float* __restrict__ u_spk) {
    int b = blockIdx.x, tid = threadIdx.x;
    int chunk = blockIdx.y * 256 + tid;          // 0..1023
    int t0 = chunk * 4;
    int start = t0 - 128; if (start < 0) start = 0;
    const float* ub = u_bn + (size_t)b * S_;
    float v = 0.f;
    for (int t = start; t < t0 + 4; t++) {
        float xv = ub[t];
        v = v + (xv - v) * 0.5f;
        float sp = (v - 1.0f) >= 0.0f ? 1.0f : 0.0f;
        if (t >= t0) u_spk[(size_t)b * S_ + t] = sp;
        v = v * (1.0f - sp);
    }
}

// ---------------------------------------------------------------- K2b: compact sorted spike lists
__global__ __launch_bounds__(256) void k_compact(const float* __restrict__ u_spk,
                                                 int* __restrict__ spk_idx,
                                                 int* __restrict__ spk_cnt) {
    __shared__ int wcnt[4];
    __shared__ int base;
    int b = blockIdx.x, tid = threadIdx.x;
    int lane = tid & 63, w = tid >> 6;
    if (tid == 0) base = 0;
    __syncthreads();
    for (int r = 0; r < 16; r++) {
        int t = r * 256 + tid;
        bool f = u_spk[(size_t)b * S_ + t] > 0.5f;
        unsigned long long bal = __ballot(f);
        int pre = __popcll(bal & (((unsigned long long)1 << lane) - 1ull));
        if (lane == 0) wcnt[w] = __popcll(bal);
        __syncthreads();
        int off = base;
        for (int i = 0; i < w; i++) off += wcnt[i];
        if (f) spk_idx[(size_t)b * S_ + off + pre] = t;
        __syncthreads();
        if (tid == 0) base += wcnt[0] + wcnt[1] + wcnt[2] + wcnt[3];
        __syncthreads();
    }
    if (tid == 0) spk_cnt[b] = base;
}

// ---------------------------------------------------------------- K3: sparse conv + BN(m)  -> m_bn [B,M,S]
// Zero-padded H in LDS: Hpad[0..S)=0, Hpad[S+t]=H[ch,t].  acc[i] covers t=tid+256*i.
// Per spike (wave-uniform tau): 16 independent conflict-free ds_read_b32 + adds.
__global__ __launch_bounds__(256) void k_conv(const float* __restrict__ H,
                                              const int* __restrict__ spk_idx,
                                              const int* __restrict__ spk_cnt,
                                              const float* __restrict__ g_m,
                                              const float* __restrict__ b_m,
                                              const float* __restrict__ mu_m,
                                              const float* __restrict__ var_m,
                                              float* __restrict__ m_bn) {
    __shared__ float Hpad[2 * S_];
    __shared__ int spk[S_];
    int bid = blockIdx.x;
    int b = bid >> 8, ch = bid & 255;
    int tid = threadIdx.x;
    float4* Hz = (float4*)Hpad;
    for (int i = tid; i < S_ / 4; i += 256) Hz[i] = make_float4(0.f, 0.f, 0.f, 0.f);
    const float4* Hv = (const float4*)(H + (size_t)ch * S_);
    float4* Hu = (float4*)(Hpad + S_);
    for (int i = tid; i < S_ / 4; i += 256) Hu[i] = Hv[i];
    int n = spk_cnt[b];
    const int* sl = spk_idx + (size_t)b * S_;
    for (int i = tid; i < n; i += 256) spk[i] = sl[i];
    __syncthreads();

    float acc[16];
    #pragma unroll
    for (int i = 0; i < 16; i++) acc[i] = 0.f;
    const float* base = Hpad + S_ + tid;

    #pragma unroll 2
    for (int j = 0; j < n; j++) {
        int tau = spk[j];
        const float* hp = base - tau;
        if (tau < 2048) {      // wave-uniform; lower half all-zero when tau>=2048
            #pragma unroll
            for (int i = 0; i < 8; i++) acc[i] += hp[256 * i];
        }
        #pragma unroll
        for (int i = 8; i < 16; i++) acc[i] += hp[256 * i];
    }

    float g = g_m[ch], bb = b_m[ch], mu = mu_m[ch];
    float rs = 1.0f / sqrtf(var_m[ch] + EPS_);
    float* out = m_bn + ((size_t)b * M_ + ch) * S_;
    #pragma unroll
    for (int i = 0; i < 16; i++)
        out[tid + 256 * i] = g * (acc[i] - mu) * rs + bb;
}

// ---------------------------------------------------------------- K5: m-LIF (chunk 256, warm-up 128) -> m_s [B,S,M]
__global__ __launch_bounds__(256) void k_mlif(const float* __restrict__ m_bn,
                                              float* __restrict__ m_s) {
    int b = blockIdx.x;
    int ch = blockIdx.y * 64 + threadIdx.x;
    int c = blockIdx.z * 4 + threadIdx.y;        // 0..15
    int t0 = c * 256;
    int start = t0 - 128; if (start < 0) start = 0;
    const float* src = m_bn + ((size_t)b * M_ + ch) * S_;
    float v = 0.f;
    for (int t = start; t < t0 + 256; t += 4) {
        float4 xv = *(const float4*)(src + t);
        float xs[4] = {xv.x, xv.y, xv.z, xv.w};
        #pragma unroll
        for (int u = 0; u < 4; u++) {
            int t2 = t + u;
            v = v + (xs[u] - v) * 0.5f;
            float sp = (v - 1.0f) >= 0.0f ? 1.0f : 0.0f;
            if (t2 >= t0) m_s[((size_t)b * S_ + t2) * M_ + ch] = sp;
            v = v * (1.0f - sp);
        }
    }
}

// ---------------------------------------------------------------- K6: h GEMM (fp32) + bias + BN(h) -> h_bn [B*S, HD]
__global__ __launch_bounds__(256) void k_hgemm(const float* __restrict__ m_s,
                                               const float* __restrict__ x,
                                               const float* __restrict__ W,
                                               const float* __restrict__ Wb,
                                               const float* __restrict__ g_h,
                                               const float* __restrict__ b_h,
                                               const float* __restrict__ mu_h,
                                               const float* __restrict__ var_h,
                                               float* __restrict__ h_bn) {
    __shared__ float AsT[64 * 68];
    __shared__ float Bs[64 * 68];
    int tid = threadIdx.x;
    int row0 = blockIdx.x * 64, col0 = blockIdx.y * 64;
    int tx = tid & 15, ty = tid >> 4;
    int lr = tid >> 2, kq = tid & 3;
    float acc[4][4] = {};
    for (int kt = 0; kt < 6; kt++) {
        const float* Abase;
        if (kt < 4) Abase = m_s + (size_t)(row0 + lr) * M_ + kt * 64;
        else        Abase = x   + (size_t)(row0 + lr) * I_ + (kt - 4) * 64;
        #pragma unroll
        for (int i = 0; i < 4; i++) {
            int kl = kq * 16 + i * 4;
            float4 v = *(const float4*)(Abase + kl);
            AsT[(kl + 0) * 68 + lr] = v.x;
            AsT[(kl + 1) * 68 + lr] = v.y;
            AsT[(kl + 2) * 68 + lr] = v.z;
            AsT[(kl + 3) * 68 + lr] = v.w;
        }
        const float* Bbase = W + (size_t)(col0 + lr) * K_ + kt * 64;
        #pragma unroll
        for (int i = 0; i < 4; i++) {
            int kl = kq * 16 + i * 4;
            float4 v = *(const float4*)(Bbase + kl);
            Bs[(kl + 0) * 68 + lr] = v.x;
            Bs[(kl + 1) * 68 + lr] = v.y;
            Bs[(kl + 2) * 68 + lr] = v.z;
            Bs[(kl + 3) * 68 + lr] = v.w;
        }
        __syncthreads();
        #pragma unroll 4
        for (int kk = 0; kk < 64; kk++) {
            float4 a  = *(const float4*)&AsT[kk * 68 + ty * 4];
            float4 bv = *(const float4*)&Bs[kk * 68 + tx * 4];
            float av[4] = {a.x, a.y, a.z, a.w};
            float bw[4] = {bv.x, bv.y, bv.z, bv.w};
            #pragma unroll
            for (int r = 0; r < 4; r++)
                #pragma unroll
                for (int cjj = 0; cjj < 4; cjj++)
                    acc[r][cjj] += av[r] * bw[cjj];
        }
        __syncthreads();
    }
    int col = col0 + tx * 4;
    float4 g4  = *(const float4*)(g_h + col);
    float4 b4  = *(const float4*)(b_h + col);
    float4 mu4 = *(const float4*)(mu_h + col);
    float4 va4 = *(const float4*)(var_h + col);
    float4 wb4 = *(const float4*)(Wb + col);
    float gg[4]  = {g4.x, g4.y, g4.z, g4.w};
    float bbv[4] = {b4.x, b4.y, b4.z, b4.w};
    float mm[4]  = {mu4.x, mu4.y, mu4.z, mu4.w};
    float vv[4]  = {va4.x, va4.y, va4.z, va4.w};
    float wb[4]  = {wb4.x, wb4.y, wb4.z, wb4.w};
    float rs[4];
    #pragma unroll
    for (int j = 0; j < 4; j++) rs[j] = 1.0f / sqrtf(vv[j] + EPS_);
    #pragma unroll
    for (int r = 0; r < 4; r++) {
        int row = row0 + ty * 4 + r;
        float o[4];
        #pragma unroll
        for (int j = 0; j < 4; j++)
            o[j] = gg[j] * ((acc[r][j] + wb[j]) - mm[j]) * rs[j] + bbv[j];
        float4 o4 = {o[0], o[1], o[2], o[3]};
        *(float4*)(h_bn + (size_t)row * HD_ + col) = o4;
    }
}

// ---------------------------------------------------------------- K7: h-LIF (chunk 256, warm-up 128) -> out
__global__ __launch_bounds__(256) void k_hlif(const float* __restrict__ h_bn,
                                              float* __restrict__ out) {
    int b = blockIdx.x;
    int j = blockIdx.y * 64 + threadIdx.x;
    int c = blockIdx.z * 4 + threadIdx.y;        // 0..15
    int t0 = c * 256;
    int start = t0 - 128; if (start < 0) start = 0;
    float* hn = out + (size_t)B_ * S_ * HD_;
    float v = 0.f;
    for (int t = start; t < t0 + 256; t++) {
        float xv = h_bn[((size_t)b * S_ + t) * HD_ + j];
        v = v + (xv - v) * 0.5f;
        float sp = (v - 1.0f) >= 0.0f ? 1.0f : 0.0f;
        if (t >= t0) {
            out[((size_t)b * S_ + t) * HD_ + j] = sp;
            if (t == S_ - 1) hn[(size_t)b * HD_ + j] = sp;
        }
        v = v * (1.0f - sp);
    }
}

// ---------------------------------------------------------------- launch
extern "C" void kernel_launch(void* const* d_in, const int* in_sizes, int n_in,
                              void* d_out, int out_size, void* d_ws, size_t ws_size,
                              hipStream_t stream) {
    const float* x     = (const float*)d_in[0];
    const float* H     = (const float*)d_in[1];
    const float* Wu    = (const float*)d_in[2];
    const float* Wub   = (const float*)d_in[3];
    const float* Wh    = (const float*)d_in[4];
    const float* Whb   = (const float*)d_in[5];
    const float* g_u   = (const float*)d_in[6];
    const float* b_u   = (const float*)d_in[7];
    const float* mu_u  = (const float*)d_in[8];
    const float* var_u = (const float*)d_in[9];
    const float* g_m   = (const float*)d_in[10];
    const float* b_m   = (const float*)d_in[11];
    const float* mu_m  = (const float*)d_in[12];
    const float* var_m = (const float*)d_in[13];
    const float* g_h   = (const float*)d_in[14];
    const float* b_h   = (const float*)d_in[15];
    const float* mu_h  = (const float*)d_in[16];
    const float* var_h = (const float*)d_in[17];

    float* ws    = (float*)d_ws;
    float* u_bn  = ws;                               // 65536
    float* u_spk = ws + 65536;                       // 65536
    int*   spk_idx = (int*)(ws + 131072);            // 65536 ints
    int*   spk_cnt = (int*)(ws + 196608);            // 16 ints
    float* m_bn  = ws + 200704;                      // 16777216  [B,M,S]
    float* m_s   = m_bn + 16777216;                  // 16777216  [B,S,M]
    float* h_bn  = m_s + 16777216;                   // 25165824  [B*S,HD]

    k_upre<<<dim3(256), dim3(256), 0, stream>>>(x, Wu, Wub, g_u, b_u, mu_u, var_u, u_bn);
    k_ulif<<<dim3(16, 4), dim3(256), 0, stream>>>(u_bn, u_spk);
    k_compact<<<dim3(16), dim3(256), 0, stream>>>(u_spk, spk_idx, spk_cnt);
    k_conv<<<dim3(4096), dim3(256), 0, stream>>>(H, spk_idx, spk_cnt,
                                                 g_m, b_m, mu_m, var_m, m_bn);
    k_mlif<<<dim3(16, 4, 4), dim3(64, 4), 0, stream>>>(m_bn, m_s);
    k_hgemm<<<dim3(1024, 6), dim3(256), 0, stream>>>(m_s, x, Wh, Whb,
                                                     g_h, b_h, mu_h, var_h, h_bn);
    k_hlif<<<dim3(16, 6, 4), dim3(64, 4), 0, stream>>>(h_bn, (float*)d_out);
}